// Round 1
// baseline (5722.710 us; speedup 1.0000x reference)
//
#include <hip/hip_runtime.h>
#include <math.h>

#define HID 2048
#define ITR 1024
#define NEXP 8
#define TOPK 2
#define NTOK 2048
#define NSLOT (NTOK * TOPK)

#define TT 8            // token-slots per block
#define TN 128          // i/h tile
#define TK 16           // k tile
#define WPAD 20         // padded LDS row width (floats) for weight tiles
#define IPAD 1028       // padded LDS row width for inter
#define MAXTILES (NSLOT / TT)   // 512

// ---------------- routing: bucket the 4096 (token, weight) slots per expert ----------------
__global__ void route_k(const int* __restrict__ idx,
                        const float* __restrict__ wts,
                        int* __restrict__ counts,
                        int* __restrict__ btok,
                        float* __restrict__ bw) {
    int s = blockIdx.x * blockDim.x + threadIdx.x;
    if (s >= NSLOT) return;
    int e = idx[s];
    int pos = atomicAdd(&counts[e], 1);
    btok[(size_t)e * NSLOT + pos] = s / TOPK;   // token id
    bw[(size_t)e * NSLOT + pos] = wts[s];
}

// ---------------- fused expert MLP over an 8-token-slot tile ----------------
__launch_bounds__(256)
__global__ void moe_k(const float* __restrict__ x,
                      const float* __restrict__ gate,
                      const float* __restrict__ up,
                      const float* __restrict__ down,
                      const int* __restrict__ counts,
                      const int* __restrict__ btok,
                      const float* __restrict__ bw,
                      float* __restrict__ out) {
    const int e = blockIdx.x / MAXTILES;
    const int tile = blockIdx.x % MAXTILES;
    const int n = counts[e];
    const int t0 = tile * TT;
    if (t0 >= n) return;

    __shared__ float s_wg[TN][WPAD];   // 10.2 KB
    __shared__ float s_wu[TN][WPAD];   // 10.2 KB
    __shared__ float s_it[TT][IPAD];   // 32.9 KB
    __shared__ int   s_tok[TT];
    __shared__ float s_w[TT];

    const int tid = threadIdx.x;
    if (tid < TT) {
        int tt = t0 + tid;
        bool v = tt < n;
        s_tok[tid] = btok[(size_t)e * NSLOT + (v ? tt : t0)];  // clamp to a valid token
        s_w[tid] = v ? bw[(size_t)e * NSLOT + tt] : 0.0f;      // padded rows add 0
    }
    __syncthreads();

    const int tok = tid >> 5;           // 0..7  (32 threads per token row)
    const int ic  = (tid & 31) << 2;    // 4 consecutive output cols in [0, TN)
    const int mytok = s_tok[tok];
    const float* xrow = x + (size_t)mytok * HID;

    const float* gbase = gate + (size_t)e * ITR * HID;
    const float* ubase = up   + (size_t)e * ITR * HID;
    const float* dbase = down + (size_t)e * HID * ITR;

    // ---------- Stage 1: inter = silu(x @ G^T) * (x @ U^T)  -> s_it ----------
    for (int i0 = 0; i0 < ITR; i0 += TN) {
        float ag[4] = {0.f, 0.f, 0.f, 0.f};
        float au[4] = {0.f, 0.f, 0.f, 0.f};
        for (int k0 = 0; k0 < HID; k0 += TK) {
            // stage gate+up weight tiles: TN x TK floats each = 512 float4 per tile
            #pragma unroll
            for (int j = 0; j < 2; ++j) {
                int f4 = tid + j * 256;
                int r = f4 >> 2;             // row in [0,128)
                int c = (f4 & 3) << 2;       // col {0,4,8,12}
                *(float4*)&s_wg[r][c] = *(const float4*)(gbase + (size_t)(i0 + r) * HID + k0 + c);
                *(float4*)&s_wu[r][c] = *(const float4*)(ubase + (size_t)(i0 + r) * HID + k0 + c);
            }
            __syncthreads();
            #pragma unroll
            for (int kk = 0; kk < TK; kk += 4) {
                float4 xv = *(const float4*)(xrow + k0 + kk);   // wave-broadcast, L1 hit
                #pragma unroll
                for (int q = 0; q < 4; ++q) {
                    float4 wg = *(const float4*)&s_wg[ic + q][kk];
                    float4 wu = *(const float4*)&s_wu[ic + q][kk];
                    ag[q] += xv.x * wg.x + xv.y * wg.y + xv.z * wg.z + xv.w * wg.w;
                    au[q] += xv.x * wu.x + xv.y * wu.y + xv.z * wu.z + xv.w * wu.w;
                }
            }
            __syncthreads();
        }
        #pragma unroll
        for (int q = 0; q < 4; ++q) {
            float g = ag[q], u = au[q];
            float sg = g / (1.0f + __expf(-g));   // silu
            s_it[tok][i0 + ic + q] = sg * u;
        }
    }
    __syncthreads();

    // ---------- Stage 2: out[tok] += w * (inter @ D^T) ----------
    const float wscale = s_w[tok];
    for (int h0 = 0; h0 < HID; h0 += TN) {
        float ac[4] = {0.f, 0.f, 0.f, 0.f};
        for (int k0 = 0; k0 < ITR; k0 += TK) {
            #pragma unroll
            for (int j = 0; j < 2; ++j) {
                int f4 = tid + j * 256;
                int r = f4 >> 2;
                int c = (f4 & 3) << 2;
                *(float4*)&s_wg[r][c] = *(const float4*)(dbase + (size_t)(h0 + r) * ITR + k0 + c);
            }
            __syncthreads();
            #pragma unroll
            for (int kk = 0; kk < TK; kk += 4) {
                float4 xv = *(const float4*)&s_it[tok][k0 + kk];   // broadcast read
                #pragma unroll
                for (int q = 0; q < 4; ++q) {
                    float4 w = *(const float4*)&s_wg[ic + q][kk];
                    ac[q] += xv.x * w.x + xv.y * w.y + xv.z * w.z + xv.w * w.w;
                }
            }
            __syncthreads();
        }
        float* orow = out + (size_t)mytok * HID + h0 + ic;
        #pragma unroll
        for (int q = 0; q < 4; ++q) {
            atomicAdd(&orow[q], wscale * ac[q]);   // exactly 2 adders per element
        }
    }
}

extern "C" void kernel_launch(void* const* d_in, const int* in_sizes, int n_in,
                              void* d_out, int out_size, void* d_ws, size_t ws_size,
                              hipStream_t stream) {
    const float* x    = (const float*)d_in[0];
    const int*   idx  = (const int*)d_in[1];
    const float* wts  = (const float*)d_in[2];
    const float* gate = (const float*)d_in[3];
    const float* up   = (const float*)d_in[4];
    const float* down = (const float*)d_in[5];
    float* out = (float*)d_out;

    // workspace layout: [counts: 256 B][btok: 8*4096 int][bw: 8*4096 float]  ~= 262 KB
    int*   counts = (int*)d_ws;
    int*   btok   = (int*)((char*)d_ws + 256);
    float* bw     = (float*)((char*)d_ws + 256 + (size_t)NEXP * NSLOT * sizeof(int));

    hipMemsetAsync(d_out, 0, (size_t)out_size * sizeof(float), stream);
    hipMemsetAsync(counts, 0, 256, stream);

    route_k<<<dim3((NSLOT + 255) / 256), dim3(256), 0, stream>>>(idx, wts, counts, btok, bw);
    moe_k<<<dim3(NEXP * MAXTILES), dim3(256), 0, stream>>>(x, gate, up, down, counts, btok, bw, out);
}

// Round 2
// 1176.704 us; speedup vs baseline: 4.8633x; 4.8633x over previous
//
#include <hip/hip_runtime.h>
#include <math.h>

#define HID 2048
#define ITR 1024
#define NEXP 8
#define TOPK 2
#define NTOK 2048
#define NSLOT (NTOK * TOPK)

typedef __attribute__((ext_vector_type(8))) short short8;
typedef __attribute__((ext_vector_type(4))) float f32x4;

__device__ __forceinline__ unsigned short f2bf(float f) {
    unsigned u = __float_as_uint(f);
    u += 0x7FFFu + ((u >> 16) & 1u);
    return (unsigned short)(u >> 16);
}

// ---------------- routing: bucket the 4096 (token, weight) slots per expert ----------------
__global__ void route_k(const int* __restrict__ idx,
                        const float* __restrict__ wts,
                        int* __restrict__ counts,
                        int* __restrict__ btok,
                        float* __restrict__ bw) {
    int s = blockIdx.x * blockDim.x + threadIdx.x;
    if (s >= NSLOT) return;
    int e = idx[s];
    int pos = atomicAdd(&counts[e], 1);
    btok[(size_t)e * NSLOT + pos] = s / TOPK;
    bw[(size_t)e * NSLOT + pos] = wts[s];
}

// offsets into the compacted, 128-row-padded inter buffer
__global__ void prefix_k(const int* __restrict__ counts, int* __restrict__ off) {
    if (threadIdx.x == 0 && blockIdx.x == 0) {
        int a = 0;
        for (int e = 0; e < NEXP; ++e) {
            off[e] = a;
            a += ((counts[e] + 127) >> 7) << 7;
        }
    }
}

// x fp32 -> bf16 (one row per token; gathered later per slot)
__global__ void xconv_k(const float* __restrict__ x, unsigned short* __restrict__ xb) {
    int i = blockIdx.x * blockDim.x + threadIdx.x;  // float4 index, exact grid
    float4 v = ((const float4*)x)[i];
    ushort4 b;
    b.x = f2bf(v.x); b.y = f2bf(v.y); b.z = f2bf(v.z); b.w = f2bf(v.w);
    ((ushort4*)xb)[i] = b;
}

// ================= MFMA path =================
#define BK 64
#define LDW 72  // padded LDS row width in bf16 (144 B, 16B-aligned)

// Stage 1: inter[pos][i] = silu(x@G^T) * (x@U^T), bf16 out.
// grid: ((e*8 + iblk)*32 + tile), block 256
__launch_bounds__(256)
__global__ void moe_gu_k(const unsigned short* __restrict__ xb,
                         const float* __restrict__ gate,
                         const float* __restrict__ up,
                         const int* __restrict__ counts,
                         const int* __restrict__ btok,
                         const int* __restrict__ off,
                         unsigned short* __restrict__ interw) {
    const int tile = blockIdx.x & 31;
    const int ei   = blockIdx.x >> 5;
    const int iblk = ei & 7;
    const int e    = ei >> 3;
    const int n = counts[e];
    if (tile * 128 >= n) return;

    __shared__ unsigned short s_a[128][LDW];
    __shared__ unsigned short s_bg[128][LDW];
    __shared__ unsigned short s_bu[128][LDW];
    __shared__ int s_tok[128];

    const int tid = threadIdx.x;
    if (tid < 128) {
        int tt = tile * 128 + tid;
        s_tok[tid] = btok[e * NSLOT + (tt < n ? tt : n - 1)];
    }
    __syncthreads();

    // A staging map: chunk c = tid + t*256, row=c>>3, col=(c&7)*8 (8 bf16 = 16B)
    const unsigned short* asrc[4];
    unsigned aoff[4];
    #pragma unroll
    for (int t = 0; t < 4; ++t) {
        int c = tid + t * 256;
        int r = c >> 3, col = (c & 7) * 8;
        asrc[t] = xb + (size_t)s_tok[r] * HID + col;
        aoff[t] = r * LDW + col;
    }
    // B staging map: f = tid + t*256, row=f>>4, col=(f&15)*4 (4 fp32 -> 4 bf16)
    unsigned goff[8], loff[8];
    const float* gbase = gate + (size_t)e * ITR * HID + (size_t)iblk * 128 * HID;
    const float* ubase = up   + (size_t)e * ITR * HID + (size_t)iblk * 128 * HID;
    #pragma unroll
    for (int t = 0; t < 8; ++t) {
        int f = tid + t * 256;
        int r = f >> 4, col = (f & 15) * 4;
        goff[t] = r * HID + col;
        loff[t] = r * LDW + col;
    }

    const int lane = tid & 63;
    const int w = tid >> 6;
    const int wrow = (w & 1) * 64, wcol = (w >> 1) * 64;
    const int l15 = lane & 15, quad = lane >> 4;

    f32x4 accg[4][4], accu[4][4];
    #pragma unroll
    for (int m = 0; m < 4; ++m)
        #pragma unroll
        for (int nn = 0; nn < 4; ++nn) {
            accg[m][nn] = (f32x4){0.f, 0.f, 0.f, 0.f};
            accu[m][nn] = (f32x4){0.f, 0.f, 0.f, 0.f};
        }

    unsigned short* s_flat_a = &s_a[0][0];
    unsigned short* s_flat_g = &s_bg[0][0];
    unsigned short* s_flat_u = &s_bu[0][0];

    for (int k0 = 0; k0 < HID; k0 += BK) {
        #pragma unroll
        for (int t = 0; t < 4; ++t)
            *(uint4*)(s_flat_a + aoff[t]) = *(const uint4*)(asrc[t] + k0);
        #pragma unroll
        for (int t = 0; t < 8; ++t) {
            float4 g = *(const float4*)(gbase + goff[t] + k0);
            float4 u = *(const float4*)(ubase + goff[t] + k0);
            ushort4 gb, ub;
            gb.x = f2bf(g.x); gb.y = f2bf(g.y); gb.z = f2bf(g.z); gb.w = f2bf(g.w);
            ub.x = f2bf(u.x); ub.y = f2bf(u.y); ub.z = f2bf(u.z); ub.w = f2bf(u.w);
            *(ushort4*)(s_flat_g + loff[t]) = gb;
            *(ushort4*)(s_flat_u + loff[t]) = ub;
        }
        __syncthreads();
        #pragma unroll
        for (int kk = 0; kk < 2; ++kk) {
            const int kc = kk * 32 + quad * 8;
            short8 af[4], bg[4], bu[4];
            #pragma unroll
            for (int m = 0; m < 4; ++m)
                af[m] = *(const short8*)&s_a[wrow + m * 16 + l15][kc];
            #pragma unroll
            for (int nn = 0; nn < 4; ++nn) {
                bg[nn] = *(const short8*)&s_bg[wcol + nn * 16 + l15][kc];
                bu[nn] = *(const short8*)&s_bu[wcol + nn * 16 + l15][kc];
            }
            #pragma unroll
            for (int m = 0; m < 4; ++m)
                #pragma unroll
                for (int nn = 0; nn < 4; ++nn) {
                    accg[m][nn] = __builtin_amdgcn_mfma_f32_16x16x32_bf16(af[m], bg[nn], accg[m][nn], 0, 0, 0);
                    accu[m][nn] = __builtin_amdgcn_mfma_f32_16x16x32_bf16(af[m], bu[nn], accu[m][nn], 0, 0, 0);
                }
        }
        __syncthreads();
    }

    // epilogue: silu(g)*u -> bf16 inter
    const int pos0 = off[e] + tile * 128;
    #pragma unroll
    for (int m = 0; m < 4; ++m) {
        #pragma unroll
        for (int nn = 0; nn < 4; ++nn) {
            int col = iblk * 128 + wcol + nn * 16 + l15;
            #pragma unroll
            for (int r = 0; r < 4; ++r) {
                int row = wrow + m * 16 + quad * 4 + r;
                float g = accg[m][nn][r], u = accu[m][nn][r];
                float s = g / (1.0f + __expf(-g));
                interw[(size_t)(pos0 + row) * ITR + col] = f2bf(s * u);
            }
        }
    }
}

// Stage 2: out[tok] += w * (inter @ D^T)
// grid: ((e*16 + hblk)*32 + tile), block 256
__launch_bounds__(256)
__global__ void moe_down_k(const unsigned short* __restrict__ interw,
                           const float* __restrict__ down,
                           const int* __restrict__ counts,
                           const int* __restrict__ btok,
                           const float* __restrict__ bw,
                           const int* __restrict__ off,
                           float* __restrict__ out) {
    const int tile = blockIdx.x & 31;
    const int eh   = blockIdx.x >> 5;
    const int hblk = eh & 15;
    const int e    = eh >> 4;
    const int n = counts[e];
    if (tile * 128 >= n) return;

    __shared__ unsigned short s_a[128][LDW];
    __shared__ unsigned short s_b[128][LDW];
    __shared__ int s_tok[128];
    __shared__ float s_w[128];

    const int tid = threadIdx.x;
    if (tid < 128) {
        int tt = tile * 128 + tid;
        bool v = tt < n;
        s_tok[tid] = btok[e * NSLOT + (v ? tt : n - 1)];
        s_w[tid] = v ? bw[e * NSLOT + tt] : 0.0f;
    }
    __syncthreads();

    const int pos0 = off[e] + tile * 128;
    unsigned aoff[4], asrco[4];
    #pragma unroll
    for (int t = 0; t < 4; ++t) {
        int c = tid + t * 256;
        int r = c >> 3, col = (c & 7) * 8;
        asrco[t] = (unsigned)((pos0 + r) * ITR + col);
        aoff[t] = r * LDW + col;
    }
    unsigned boff[8], loff[8];
    const float* dbase = down + (size_t)e * HID * ITR + (size_t)hblk * 128 * ITR;
    #pragma unroll
    for (int t = 0; t < 8; ++t) {
        int f = tid + t * 256;
        int r = f >> 4, col = (f & 15) * 4;
        boff[t] = r * ITR + col;
        loff[t] = r * LDW + col;
    }

    const int lane = tid & 63;
    const int w = tid >> 6;
    const int wrow = (w & 1) * 64, wcol = (w >> 1) * 64;
    const int l15 = lane & 15, quad = lane >> 4;

    f32x4 acc[4][4];
    #pragma unroll
    for (int m = 0; m < 4; ++m)
        #pragma unroll
        for (int nn = 0; nn < 4; ++nn) acc[m][nn] = (f32x4){0.f, 0.f, 0.f, 0.f};

    unsigned short* s_flat_a = &s_a[0][0];
    unsigned short* s_flat_b = &s_b[0][0];

    for (int k0 = 0; k0 < ITR; k0 += BK) {
        #pragma unroll
        for (int t = 0; t < 4; ++t)
            *(uint4*)(s_flat_a + aoff[t]) = *(const uint4*)(interw + asrco[t] + k0);
        #pragma unroll
        for (int t = 0; t < 8; ++t) {
            float4 v = *(const float4*)(dbase + boff[t] + k0);
            ushort4 b;
            b.x = f2bf(v.x); b.y = f2bf(v.y); b.z = f2bf(v.z); b.w = f2bf(v.w);
            *(ushort4*)(s_flat_b + loff[t]) = b;
        }
        __syncthreads();
        #pragma unroll
        for (int kk = 0; kk < 2; ++kk) {
            const int kc = kk * 32 + quad * 8;
            short8 af[4], bf[4];
            #pragma unroll
            for (int m = 0; m < 4; ++m)
                af[m] = *(const short8*)&s_a[wrow + m * 16 + l15][kc];
            #pragma unroll
            for (int nn = 0; nn < 4; ++nn)
                bf[nn] = *(const short8*)&s_b[wcol + nn * 16 + l15][kc];
            #pragma unroll
            for (int m = 0; m < 4; ++m)
                #pragma unroll
                for (int nn = 0; nn < 4; ++nn)
                    acc[m][nn] = __builtin_amdgcn_mfma_f32_16x16x32_bf16(af[m], bf[nn], acc[m][nn], 0, 0, 0);
        }
        __syncthreads();
    }

    #pragma unroll
    for (int m = 0; m < 4; ++m) {
        #pragma unroll
        for (int nn = 0; nn < 4; ++nn) {
            int col = hblk * 128 + wcol + nn * 16 + l15;
            #pragma unroll
            for (int r = 0; r < 4; ++r) {
                int row = wrow + m * 16 + quad * 4 + r;
                float wv = s_w[row];
                atomicAdd(&out[(size_t)s_tok[row] * HID + col], wv * acc[m][nn][r]);
            }
        }
    }
}

// ================= fp32 fallback (round-1 kernel, used only if ws too small) =================
#define TT 8
#define TN 128
#define TK 16
#define WPAD 20
#define IPAD 1028
#define MAXTILES (NSLOT / TT)

__launch_bounds__(256)
__global__ void moe_k(const float* __restrict__ x,
                      const float* __restrict__ gate,
                      const float* __restrict__ up,
                      const float* __restrict__ down,
                      const int* __restrict__ counts,
                      const int* __restrict__ btok,
                      const float* __restrict__ bw,
                      float* __restrict__ out) {
    const int e = blockIdx.x / MAXTILES;
    const int tile = blockIdx.x % MAXTILES;
    const int n = counts[e];
    const int t0 = tile * TT;
    if (t0 >= n) return;

    __shared__ float s_wg[TN][WPAD];
    __shared__ float s_wu[TN][WPAD];
    __shared__ float s_it[TT][IPAD];
    __shared__ int   s_tok[TT];
    __shared__ float s_w[TT];

    const int tid = threadIdx.x;
    if (tid < TT) {
        int tt = t0 + tid;
        bool v = tt < n;
        s_tok[tid] = btok[(size_t)e * NSLOT + (v ? tt : t0)];
        s_w[tid] = v ? bw[(size_t)e * NSLOT + tt] : 0.0f;
    }
    __syncthreads();

    const int tok = tid >> 5;
    const int ic  = (tid & 31) << 2;
    const int mytok = s_tok[tok];
    const float* xrow = x + (size_t)mytok * HID;
    const float* gbase = gate + (size_t)e * ITR * HID;
    const float* ubase = up   + (size_t)e * ITR * HID;
    const float* dbase = down + (size_t)e * HID * ITR;

    for (int i0 = 0; i0 < ITR; i0 += TN) {
        float ag[4] = {0.f, 0.f, 0.f, 0.f};
        float au[4] = {0.f, 0.f, 0.f, 0.f};
        for (int k0 = 0; k0 < HID; k0 += TK) {
            #pragma unroll
            for (int j = 0; j < 2; ++j) {
                int f4 = tid + j * 256;
                int r = f4 >> 2, c = (f4 & 3) << 2;
                *(float4*)&s_wg[r][c] = *(const float4*)(gbase + (size_t)(i0 + r) * HID + k0 + c);
                *(float4*)&s_wu[r][c] = *(const float4*)(ubase + (size_t)(i0 + r) * HID + k0 + c);
            }
            __syncthreads();
            #pragma unroll
            for (int kk = 0; kk < TK; kk += 4) {
                float4 xv = *(const float4*)(xrow + k0 + kk);
                #pragma unroll
                for (int q = 0; q < 4; ++q) {
                    float4 wg = *(const float4*)&s_wg[ic + q][kk];
                    float4 wu = *(const float4*)&s_wu[ic + q][kk];
                    ag[q] += xv.x * wg.x + xv.y * wg.y + xv.z * wg.z + xv.w * wg.w;
                    au[q] += xv.x * wu.x + xv.y * wu.y + xv.z * wu.z + xv.w * wu.w;
                }
            }
            __syncthreads();
        }
        #pragma unroll
        for (int q = 0; q < 4; ++q) {
            float g = ag[q], u = au[q];
            s_it[tok][i0 + ic + q] = (g / (1.0f + __expf(-g))) * u;
        }
    }
    __syncthreads();

    const float wscale = s_w[tok];
    for (int h0 = 0; h0 < HID; h0 += TN) {
        float ac[4] = {0.f, 0.f, 0.f, 0.f};
        for (int k0 = 0; k0 < ITR; k0 += TK) {
            #pragma unroll
            for (int j = 0; j < 2; ++j) {
                int f4 = tid + j * 256;
                int r = f4 >> 2, c = (f4 & 3) << 2;
                *(float4*)&s_wg[r][c] = *(const float4*)(dbase + (size_t)(h0 + r) * ITR + k0 + c);
            }
            __syncthreads();
            #pragma unroll
            for (int kk = 0; kk < TK; kk += 4) {
                float4 xv = *(const float4*)&s_it[tok][k0 + kk];
                #pragma unroll
                for (int q = 0; q < 4; ++q) {
                    float4 wv = *(const float4*)&s_wg[ic + q][kk];
                    ac[q] += xv.x * wv.x + xv.y * wv.y + xv.z * wv.z + xv.w * wv.w;
                }
            }
            __syncthreads();
        }
        float* orow = out + (size_t)mytok * HID + h0 + ic;
        #pragma unroll
        for (int q = 0; q < 4; ++q) atomicAdd(&orow[q], wscale * ac[q]);
    }
}

extern "C" void kernel_launch(void* const* d_in, const int* in_sizes, int n_in,
                              void* d_out, int out_size, void* d_ws, size_t ws_size,
                              hipStream_t stream) {
    const float* x    = (const float*)d_in[0];
    const int*   idx  = (const int*)d_in[1];
    const float* wts  = (const float*)d_in[2];
    const float* gate = (const float*)d_in[3];
    const float* up   = (const float*)d_in[4];
    const float* down = (const float*)d_in[5];
    float* out = (float*)d_out;

    // ws layout
    const size_t off_btok  = 256;
    const size_t off_bw    = off_btok + (size_t)NEXP * NSLOT * 4;
    const size_t off_offs  = off_bw + (size_t)NEXP * NSLOT * 4;
    const size_t off_xb    = off_offs + 256;
    const size_t off_inter = off_xb + (size_t)NTOK * HID * 2;
    const size_t need      = off_inter + (size_t)(NSLOT + NEXP * 128) * ITR * 2;

    int*   counts = (int*)d_ws;
    int*   btok   = (int*)((char*)d_ws + off_btok);
    float* bw     = (float*)((char*)d_ws + off_bw);
    int*   offs   = (int*)((char*)d_ws + off_offs);
    unsigned short* xb     = (unsigned short*)((char*)d_ws + off_xb);
    unsigned short* interw = (unsigned short*)((char*)d_ws + off_inter);

    hipMemsetAsync(d_out, 0, (size_t)out_size * sizeof(float), stream);
    hipMemsetAsync(counts, 0, 256, stream);

    route_k<<<dim3((NSLOT + 255) / 256), dim3(256), 0, stream>>>(idx, wts, counts, btok, bw);

    if (ws_size >= need) {
        prefix_k<<<dim3(1), dim3(64), 0, stream>>>(counts, offs);
        xconv_k<<<dim3(NTOK * HID / 4 / 256), dim3(256), 0, stream>>>(x, xb);
        moe_gu_k<<<dim3(NEXP * 8 * 32), dim3(256), 0, stream>>>(xb, gate, up, counts, btok, offs, interw);
        moe_down_k<<<dim3(NEXP * 16 * 32), dim3(256), 0, stream>>>(interw, down, counts, btok, bw, offs, out);
    } else {
        moe_k<<<dim3(NEXP * MAXTILES), dim3(256), 0, stream>>>(x, gate, up, down, counts, btok, bw, out);
    }
}

// Round 3
// 523.541 us; speedup vs baseline: 10.9308x; 2.2476x over previous
//
#include <hip/hip_runtime.h>
#include <math.h>

#define HID 2048
#define ITR 1024
#define NEXP 8
#define TOPK 2
#define NTOK 2048
#define NSLOT (NTOK * TOPK)
#define MAXTT 40   // max 128-row tiles across experts (bound: 4096/128 + 7 = 39)

typedef __attribute__((ext_vector_type(8))) short short8;
typedef __attribute__((ext_vector_type(4))) float f32x4;

__device__ __forceinline__ unsigned short f2bf(float f) {
    unsigned u = __float_as_uint(f);
    u += 0x7FFFu + ((u >> 16) & 1u);
    return (unsigned short)(u >> 16);
}

// ---------------- routing ----------------
__global__ void route_k(const int* __restrict__ idx,
                        const float* __restrict__ wts,
                        int* __restrict__ counts,
                        int* __restrict__ btok,
                        float* __restrict__ bw) {
    int s = blockIdx.x * blockDim.x + threadIdx.x;
    if (s >= NSLOT) return;
    int e = idx[s];
    int pos = atomicAdd(&counts[e], 1);
    btok[(size_t)e * NSLOT + pos] = s / TOPK;
    bw[(size_t)e * NSLOT + pos] = wts[s];
}

// offsets + dense tile table: ttab[t] = (e<<16)|tile_in_expert
__global__ void prefix_k(const int* __restrict__ counts, int* __restrict__ off,
                         int* __restrict__ ttab, int* __restrict__ ntiles) {
    if (threadIdx.x == 0 && blockIdx.x == 0) {
        int a = 0, t = 0;
        for (int e = 0; e < NEXP; ++e) {
            off[e] = a;
            int nt = (counts[e] + 127) >> 7;
            for (int i = 0; i < nt; ++i) ttab[t++] = (e << 16) | i;
            a += nt << 7;
        }
        *ntiles = t;
        for (int i = t; i < MAXTT; ++i) ttab[i] = -1;
    }
}

// x fp32 -> bf16
__global__ void xconv_k(const float* __restrict__ x, unsigned short* __restrict__ xb) {
    int i = blockIdx.x * blockDim.x + threadIdx.x;
    float4 v = ((const float4*)x)[i];
    ushort4 b;
    b.x = f2bf(v.x); b.y = f2bf(v.y); b.z = f2bf(v.z); b.w = f2bf(v.w);
    ((ushort4*)xb)[i] = b;
}

// ================= MFMA path =================
#define BK 64
#define LDW 72

// Stage 1: M=128 slots x N=64 inter cols, K=2048. grid = iblk(16) x MAXTT
__launch_bounds__(256)
__global__ void moe_gu_k(const unsigned short* __restrict__ xb,
                         const float* __restrict__ gate,
                         const float* __restrict__ up,
                         const int* __restrict__ counts,
                         const int* __restrict__ btok,
                         const int* __restrict__ off,
                         const int* __restrict__ ttab,
                         unsigned short* __restrict__ interw) {
    const int tix  = blockIdx.x % MAXTT;
    const int iblk = blockIdx.x / MAXTT;           // [0,16) -> 64 cols each
    const int tt_e = ttab[tix];
    if (tt_e < 0) return;
    const int e    = tt_e >> 16;
    const int tile = tt_e & 0xFFFF;
    const int n = counts[e];

    __shared__ unsigned short s_a[128][LDW];   // 18.4 KB
    __shared__ unsigned short s_bg[64][LDW];   // 9.2 KB
    __shared__ unsigned short s_bu[64][LDW];   // 9.2 KB
    __shared__ int s_tok[128];

    const int tid = threadIdx.x;
    if (tid < 128) {
        int tt = tile * 128 + tid;
        s_tok[tid] = btok[e * NSLOT + (tt < n ? tt : n - 1)];
    }
    __syncthreads();

    // A staging: 4 chunks of 16B: c = tid + t*256, row=c>>3, col=(c&7)*8
    const unsigned short* asrc[4];
    unsigned aoff[4];
    #pragma unroll
    for (int t = 0; t < 4; ++t) {
        int c = tid + t * 256;
        int r = c >> 3, col = (c & 7) * 8;
        asrc[t] = xb + (size_t)s_tok[r] * HID + col;
        aoff[t] = r * LDW + col;
    }
    // B staging: 64x64 fp32 per proj: f = tid + t*256, row=f>>4, col=(f&15)*4
    const float* gbase = gate + (size_t)e * ITR * HID + (size_t)iblk * 64 * HID;
    const float* ubase = up   + (size_t)e * ITR * HID + (size_t)iblk * 64 * HID;
    unsigned boff[4], loff[4];
    #pragma unroll
    for (int t = 0; t < 4; ++t) {
        int f = tid + t * 256;
        int r = f >> 4, col = (f & 15) * 4;
        boff[t] = r * HID + col;
        loff[t] = r * LDW + col;
    }

    const int lane = tid & 63;
    const int w = tid >> 6;
    const int wm = (w & 1) * 64, wn = (w >> 1) * 32;
    const int l15 = lane & 15, quad = lane >> 4;

    f32x4 accg[4][2], accu[4][2];
    #pragma unroll
    for (int m = 0; m < 4; ++m)
        #pragma unroll
        for (int nn = 0; nn < 2; ++nn) {
            accg[m][nn] = (f32x4){0.f, 0.f, 0.f, 0.f};
            accu[m][nn] = (f32x4){0.f, 0.f, 0.f, 0.f};
        }

    unsigned short* s_flat_a = &s_a[0][0];
    unsigned short* s_flat_g = &s_bg[0][0];
    unsigned short* s_flat_u = &s_bu[0][0];

    // prologue prefetch
    uint4 pa[4];
    float4 pg[4], pu[4];
    #pragma unroll
    for (int t = 0; t < 4; ++t) {
        pa[t] = *(const uint4*)(asrc[t]);
        pg[t] = *(const float4*)(gbase + boff[t]);
        pu[t] = *(const float4*)(ubase + boff[t]);
    }

    for (int k0 = 0; k0 < HID; k0 += BK) {
        // write staged regs to LDS
        #pragma unroll
        for (int t = 0; t < 4; ++t) {
            *(uint4*)(s_flat_a + aoff[t]) = pa[t];
            ushort4 gb, ub;
            gb.x = f2bf(pg[t].x); gb.y = f2bf(pg[t].y); gb.z = f2bf(pg[t].z); gb.w = f2bf(pg[t].w);
            ub.x = f2bf(pu[t].x); ub.y = f2bf(pu[t].y); ub.z = f2bf(pu[t].z); ub.w = f2bf(pu[t].w);
            *(ushort4*)(s_flat_g + loff[t]) = gb;
            *(ushort4*)(s_flat_u + loff[t]) = ub;
        }
        __syncthreads();
        // prefetch next K-tile (overlaps with MFMA below)
        if (k0 + BK < HID) {
            #pragma unroll
            for (int t = 0; t < 4; ++t) {
                pa[t] = *(const uint4*)(asrc[t] + k0 + BK);
                pg[t] = *(const float4*)(gbase + boff[t] + k0 + BK);
                pu[t] = *(const float4*)(ubase + boff[t] + k0 + BK);
            }
        }
        #pragma unroll
        for (int kk = 0; kk < 2; ++kk) {
            const int kc = kk * 32 + quad * 8;
            short8 af[4], bg[2], bu[2];
            #pragma unroll
            for (int m = 0; m < 4; ++m)
                af[m] = *(const short8*)&s_a[wm + m * 16 + l15][kc];
            #pragma unroll
            for (int nn = 0; nn < 2; ++nn) {
                bg[nn] = *(const short8*)&s_bg[wn + nn * 16 + l15][kc];
                bu[nn] = *(const short8*)&s_bu[wn + nn * 16 + l15][kc];
            }
            #pragma unroll
            for (int m = 0; m < 4; ++m)
                #pragma unroll
                for (int nn = 0; nn < 2; ++nn) {
                    accg[m][nn] = __builtin_amdgcn_mfma_f32_16x16x32_bf16(af[m], bg[nn], accg[m][nn], 0, 0, 0);
                    accu[m][nn] = __builtin_amdgcn_mfma_f32_16x16x32_bf16(af[m], bu[nn], accu[m][nn], 0, 0, 0);
                }
        }
        __syncthreads();
    }

    const int pos0 = off[e] + tile * 128;
    #pragma unroll
    for (int m = 0; m < 4; ++m) {
        #pragma unroll
        for (int nn = 0; nn < 2; ++nn) {
            int col = iblk * 64 + wn + nn * 16 + l15;
            #pragma unroll
            for (int r = 0; r < 4; ++r) {
                int row = wm + m * 16 + quad * 4 + r;
                float g = accg[m][nn][r], u = accu[m][nn][r];
                float s = g / (1.0f + __expf(-g));
                interw[(size_t)(pos0 + row) * ITR + col] = f2bf(s * u);
            }
        }
    }
}

// Stage 2: M=128 slots x N=128 hid cols, K=1024. grid = hblk(16) x MAXTT
__launch_bounds__(256)
__global__ void moe_down_k(const unsigned short* __restrict__ interw,
                           const float* __restrict__ down,
                           const int* __restrict__ counts,
                           const int* __restrict__ btok,
                           const float* __restrict__ bw,
                           const int* __restrict__ off,
                           const int* __restrict__ ttab,
                           float* __restrict__ out) {
    const int tix  = blockIdx.x % MAXTT;
    const int hblk = blockIdx.x / MAXTT;           // [0,16) -> 128 cols each
    const int tt_e = ttab[tix];
    if (tt_e < 0) return;
    const int e    = tt_e >> 16;
    const int tile = tt_e & 0xFFFF;
    const int n = counts[e];

    __shared__ unsigned short s_a[128][LDW];
    __shared__ unsigned short s_b[128][LDW];
    __shared__ int s_tok[128];
    __shared__ float s_w[128];

    const int tid = threadIdx.x;
    if (tid < 128) {
        int tt = tile * 128 + tid;
        bool v = tt < n;
        s_tok[tid] = btok[e * NSLOT + (v ? tt : n - 1)];
        s_w[tid] = v ? bw[e * NSLOT + tt] : 0.0f;
    }
    __syncthreads();

    const int pos0 = off[e] + tile * 128;
    unsigned aoff[4], asrco[4];
    #pragma unroll
    for (int t = 0; t < 4; ++t) {
        int c = tid + t * 256;
        int r = c >> 3, col = (c & 7) * 8;
        asrco[t] = (unsigned)((pos0 + r) * ITR + col);
        aoff[t] = r * LDW + col;
    }
    const float* dbase = down + (size_t)e * HID * ITR + (size_t)hblk * 128 * ITR;
    unsigned boff[8], loff[8];
    #pragma unroll
    for (int t = 0; t < 8; ++t) {
        int f = tid + t * 256;
        int r = f >> 4, col = (f & 15) * 4;
        boff[t] = r * ITR + col;
        loff[t] = r * LDW + col;
    }

    const int lane = tid & 63;
    const int w = tid >> 6;
    const int wm = (w & 1) * 64, wn = (w >> 1) * 64;
    const int l15 = lane & 15, quad = lane >> 4;

    f32x4 acc[4][4];
    #pragma unroll
    for (int m = 0; m < 4; ++m)
        #pragma unroll
        for (int nn = 0; nn < 4; ++nn) acc[m][nn] = (f32x4){0.f, 0.f, 0.f, 0.f};

    unsigned short* s_flat_a = &s_a[0][0];
    unsigned short* s_flat_b = &s_b[0][0];

    uint4 pa[4];
    float4 pb[8];
    #pragma unroll
    for (int t = 0; t < 4; ++t) pa[t] = *(const uint4*)(interw + asrco[t]);
    #pragma unroll
    for (int t = 0; t < 8; ++t) pb[t] = *(const float4*)(dbase + boff[t]);

    for (int k0 = 0; k0 < ITR; k0 += BK) {
        #pragma unroll
        for (int t = 0; t < 4; ++t)
            *(uint4*)(s_flat_a + aoff[t]) = pa[t];
        #pragma unroll
        for (int t = 0; t < 8; ++t) {
            ushort4 b;
            b.x = f2bf(pb[t].x); b.y = f2bf(pb[t].y); b.z = f2bf(pb[t].z); b.w = f2bf(pb[t].w);
            *(ushort4*)(s_flat_b + loff[t]) = b;
        }
        __syncthreads();
        if (k0 + BK < ITR) {
            #pragma unroll
            for (int t = 0; t < 4; ++t) pa[t] = *(const uint4*)(interw + asrco[t] + k0 + BK);
            #pragma unroll
            for (int t = 0; t < 8; ++t) pb[t] = *(const float4*)(dbase + boff[t] + k0 + BK);
        }
        #pragma unroll
        for (int kk = 0; kk < 2; ++kk) {
            const int kc = kk * 32 + quad * 8;
            short8 af[4], bf[4];
            #pragma unroll
            for (int m = 0; m < 4; ++m)
                af[m] = *(const short8*)&s_a[wm + m * 16 + l15][kc];
            #pragma unroll
            for (int nn = 0; nn < 4; ++nn)
                bf[nn] = *(const short8*)&s_b[wn + nn * 16 + l15][kc];
            #pragma unroll
            for (int m = 0; m < 4; ++m)
                #pragma unroll
                for (int nn = 0; nn < 4; ++nn)
                    acc[m][nn] = __builtin_amdgcn_mfma_f32_16x16x32_bf16(af[m], bf[nn], acc[m][nn], 0, 0, 0);
        }
        __syncthreads();
    }

    #pragma unroll
    for (int m = 0; m < 4; ++m) {
        #pragma unroll
        for (int nn = 0; nn < 4; ++nn) {
            int col = hblk * 128 + wn + nn * 16 + l15;
            #pragma unroll
            for (int r = 0; r < 4; ++r) {
                int row = wm + m * 16 + quad * 4 + r;
                float wv = s_w[row];
                atomicAdd(&out[(size_t)s_tok[row] * HID + col], wv * acc[m][nn][r]);
            }
        }
    }
}

// ================= fp32 fallback (used only if ws too small) =================
#define TT 8
#define TN 128
#define TK 16
#define WPAD 20
#define IPAD 1028
#define MAXTILES (NSLOT / TT)

__launch_bounds__(256)
__global__ void moe_k(const float* __restrict__ x,
                      const float* __restrict__ gate,
                      const float* __restrict__ up,
                      const float* __restrict__ down,
                      const int* __restrict__ counts,
                      const int* __restrict__ btok,
                      const float* __restrict__ bw,
                      float* __restrict__ out) {
    const int e = blockIdx.x / MAXTILES;
    const int tile = blockIdx.x % MAXTILES;
    const int n = counts[e];
    const int t0 = tile * TT;
    if (t0 >= n) return;

    __shared__ float s_wg[TN][WPAD];
    __shared__ float s_wu[TN][WPAD];
    __shared__ float s_it[TT][IPAD];
    __shared__ int   s_tok[TT];
    __shared__ float s_w[TT];

    const int tid = threadIdx.x;
    if (tid < TT) {
        int tt = t0 + tid;
        bool v = tt < n;
        s_tok[tid] = btok[(size_t)e * NSLOT + (v ? tt : t0)];
        s_w[tid] = v ? bw[(size_t)e * NSLOT + tt] : 0.0f;
    }
    __syncthreads();

    const int tok = tid >> 5;
    const int ic  = (tid & 31) << 2;
    const int mytok = s_tok[tok];
    const float* xrow = x + (size_t)mytok * HID;
    const float* gbase = gate + (size_t)e * ITR * HID;
    const float* ubase = up   + (size_t)e * ITR * HID;
    const float* dbase = down + (size_t)e * HID * ITR;

    for (int i0 = 0; i0 < ITR; i0 += TN) {
        float ag[4] = {0.f, 0.f, 0.f, 0.f};
        float au[4] = {0.f, 0.f, 0.f, 0.f};
        for (int k0 = 0; k0 < HID; k0 += TK) {
            #pragma unroll
            for (int j = 0; j < 2; ++j) {
                int f4 = tid + j * 256;
                int r = f4 >> 2, c = (f4 & 3) << 2;
                *(float4*)&s_wg[r][c] = *(const float4*)(gbase + (size_t)(i0 + r) * HID + k0 + c);
                *(float4*)&s_wu[r][c] = *(const float4*)(ubase + (size_t)(i0 + r) * HID + k0 + c);
            }
            __syncthreads();
            #pragma unroll
            for (int kk = 0; kk < TK; kk += 4) {
                float4 xv = *(const float4*)(xrow + k0 + kk);
                #pragma unroll
                for (int q = 0; q < 4; ++q) {
                    float4 wg = *(const float4*)&s_wg[ic + q][kk];
                    float4 wu = *(const float4*)&s_wu[ic + q][kk];
                    ag[q] += xv.x * wg.x + xv.y * wg.y + xv.z * wg.z + xv.w * wg.w;
                    au[q] += xv.x * wu.x + xv.y * wu.y + xv.z * wu.z + xv.w * wu.w;
                }
            }
            __syncthreads();
        }
        #pragma unroll
        for (int q = 0; q < 4; ++q) {
            float g = ag[q], u = au[q];
            s_it[tok][i0 + ic + q] = (g / (1.0f + __expf(-g))) * u;
        }
    }
    __syncthreads();

    const float wscale = s_w[tok];
    for (int h0 = 0; h0 < HID; h0 += TN) {
        float ac[4] = {0.f, 0.f, 0.f, 0.f};
        for (int k0 = 0; k0 < ITR; k0 += TK) {
            #pragma unroll
            for (int j = 0; j < 2; ++j) {
                int f4 = tid + j * 256;
                int r = f4 >> 2, c = (f4 & 3) << 2;
                *(float4*)&s_wg[r][c] = *(const float4*)(dbase + (size_t)(h0 + r) * ITR + k0 + c);
            }
            __syncthreads();
            #pragma unroll
            for (int kk = 0; kk < TK; kk += 4) {
                float4 xv = *(const float4*)&s_it[tok][k0 + kk];
                #pragma unroll
                for (int q = 0; q < 4; ++q) {
                    float4 wv = *(const float4*)&s_wg[ic + q][kk];
                    ac[q] += xv.x * wv.x + xv.y * wv.y + xv.z * wv.z + xv.w * wv.w;
                }
            }
            __syncthreads();
        }
        float* orow = out + (size_t)mytok * HID + h0 + ic;
        #pragma unroll
        for (int q = 0; q < 4; ++q) atomicAdd(&orow[q], wscale * ac[q]);
    }
}

extern "C" void kernel_launch(void* const* d_in, const int* in_sizes, int n_in,
                              void* d_out, int out_size, void* d_ws, size_t ws_size,
                              hipStream_t stream) {
    const float* x    = (const float*)d_in[0];
    const int*   idx  = (const int*)d_in[1];
    const float* wts  = (const float*)d_in[2];
    const float* gate = (const float*)d_in[3];
    const float* up   = (const float*)d_in[4];
    const float* down = (const float*)d_in[5];
    float* out = (float*)d_out;

    // ws layout
    const size_t off_btok  = 256;
    const size_t off_bw    = off_btok + (size_t)NEXP * NSLOT * 4;
    const size_t off_offs  = off_bw + (size_t)NEXP * NSLOT * 4;   // offs[8] | ttab[40] | ntiles
    const size_t off_xb    = off_offs + 256;
    const size_t off_inter = off_xb + (size_t)NTOK * HID * 2;
    const size_t need      = off_inter + (size_t)(NSLOT + NEXP * 128) * ITR * 2;

    int*   counts = (int*)d_ws;
    int*   btok   = (int*)((char*)d_ws + off_btok);
    float* bw     = (float*)((char*)d_ws + off_bw);
    int*   offs   = (int*)((char*)d_ws + off_offs);
    int*   ttab   = offs + 8;
    int*   ntiles = offs + 8 + MAXTT;
    unsigned short* xb     = (unsigned short*)((char*)d_ws + off_xb);
    unsigned short* interw = (unsigned short*)((char*)d_ws + off_inter);

    hipMemsetAsync(d_out, 0, (size_t)out_size * sizeof(float), stream);
    hipMemsetAsync(counts, 0, 256, stream);

    route_k<<<dim3((NSLOT + 255) / 256), dim3(256), 0, stream>>>(idx, wts, counts, btok, bw);

    if (ws_size >= need) {
        prefix_k<<<dim3(1), dim3(64), 0, stream>>>(counts, offs, ttab, ntiles);
        xconv_k<<<dim3(NTOK * HID / 4 / 256), dim3(256), 0, stream>>>(x, xb);
        moe_gu_k<<<dim3(16 * MAXTT), dim3(256), 0, stream>>>(xb, gate, up, counts, btok, offs, ttab, interw);
        moe_down_k<<<dim3(16 * MAXTT), dim3(256), 0, stream>>>(interw, down, counts, btok, bw, offs, ttab, out);
    } else {
        moe_k<<<dim3(NEXP * MAXTILES), dim3(256), 0, stream>>>(x, gate, up, down, counts, btok, bw, out);
    }
}

// Round 4
// 440.525 us; speedup vs baseline: 12.9907x; 1.1884x over previous
//
#include <hip/hip_runtime.h>
#include <math.h>

#define HID 2048
#define ITR 1024
#define NEXP 8
#define TOPK 2
#define NTOK 2048
#define NSLOT (NTOK * TOPK)
#define MAXTT 40        // max 128-row tiles across experts (bound 4096/128+7=39)
#define SLOTS 80        // per-XCD slot count for block tables (bound 2*39=78)

typedef __attribute__((ext_vector_type(8))) short short8;
typedef __attribute__((ext_vector_type(4))) float f32x4;

__device__ __forceinline__ unsigned short f2bf(float f) {
    unsigned u = __float_as_uint(f);
    u += 0x7FFFu + ((u >> 16) & 1u);
    return (unsigned short)(u >> 16);
}

// ---------------- fused routing: histogram + offsets + scatter + XCD-grouped block tables ----------------
// single block, 256 threads
__global__ void route_all_k(const int* __restrict__ idx,
                            const float* __restrict__ wts,
                            int* __restrict__ counts_g,
                            int* __restrict__ btok,
                            float* __restrict__ bw,
                            int* __restrict__ offs_g,
                            int* __restrict__ slotmap,
                            int* __restrict__ gu_tab,
                            int* __restrict__ dn_tab) {
    __shared__ int h[NEXP], nt[NEXP], pre[NEXP], base[NEXP], cur[NEXP];
    const int tid = threadIdx.x;
    if (tid < NEXP) { h[tid] = 0; cur[tid] = 0; }
    __syncthreads();
    for (int s = tid; s < NSLOT; s += 256) atomicAdd(&h[idx[s]], 1);
    __syncthreads();
    if (tid == 0) {
        int a = 0;
        for (int e = 0; e < NEXP; ++e) {
            base[e] = a; counts_g[e] = h[e]; offs_g[e] = a;
            int t = (h[e] + 127) >> 7; nt[e] = t; a += t << 7;
        }
        int p = 0;
        for (int e = 0; e < NEXP; ++e) { pre[e] = p; p += nt[e]; }
    }
    __syncthreads();
    // scatter slots into per-expert compact arrays; record global row per slot
    for (int s = tid; s < NSLOT; s += 256) {
        int e = idx[s];
        int p = atomicAdd(&cur[e], 1);
        btok[e * NSLOT + p] = s >> 1;          // token id (TOPK=2)
        bw[e * NSLOT + p] = wts[s];
        slotmap[s] = base[e] + p;              // global compact row
    }
    // block tables: prefill -1
    for (int i = tid; i < 8 * SLOTS; i += 256) { gu_tab[i] = -1; dn_tab[i] = -1; }
    __syncthreads();
    // fill: chunk c = e*16 + nchunk; xcd = nchunk&7 (16 = 0 mod 8), rank = nchunk>>3
    if (tid < 128) {
        int c = tid, e = c >> 4, ib = c & 15;
        int sb = 2 * pre[e] + (ib >> 3) * nt[e];
        for (int j = 0; j < nt[e]; ++j)
            gu_tab[(sb + j) * 8 + (ib & 7)] = (e << 16) | (ib << 8) | j;
    } else {
        int c = tid - 128, e = c >> 4, ib = c & 15;
        int sb = 2 * pre[e] + (ib >> 3) * nt[e];
        for (int j = 0; j < nt[e]; ++j)
            dn_tab[(sb + j) * 8 + (ib & 7)] = (e << 16) | (ib << 8) | j;
    }
}

// x fp32 -> bf16
__global__ void xconv_k(const float* __restrict__ x, unsigned short* __restrict__ xb) {
    int i = blockIdx.x * blockDim.x + threadIdx.x;
    float4 v = ((const float4*)x)[i];
    ushort4 b;
    b.x = f2bf(v.x); b.y = f2bf(v.y); b.z = f2bf(v.z); b.w = f2bf(v.w);
    ((ushort4*)xb)[i] = b;
}

// combine: out[t] = part[slot0[t]] + part[slot1[t]]  (weights already applied)
__global__ void combine_k(const float* __restrict__ part,
                          const int* __restrict__ slotmap,
                          float* __restrict__ out) {
    int gid = blockIdx.x * 256 + threadIdx.x;   // float4 id, NTOK*HID/4 total
    int t = gid >> 9;                           // / (HID/4=512)
    int c = gid & 511;
    int s0 = slotmap[t * 2], s1 = slotmap[t * 2 + 1];
    float4 a = ((const float4*)part)[(size_t)s0 * 512 + c];
    float4 b = ((const float4*)part)[(size_t)s1 * 512 + c];
    float4 r; r.x = a.x + b.x; r.y = a.y + b.y; r.z = a.z + b.z; r.w = a.w + b.w;
    ((float4*)out)[gid] = r;
}

// ================= MFMA path =================
#define BK 64
#define LDW 72

// Stage 1: M=128 slots x N=64 inter cols, K=2048. grid = 8*SLOTS via gu_tab
__launch_bounds__(256)
__global__ void moe_gu_k(const unsigned short* __restrict__ xb,
                         const float* __restrict__ gate,
                         const float* __restrict__ up,
                         const int* __restrict__ counts,
                         const int* __restrict__ btok,
                         const int* __restrict__ off,
                         const int* __restrict__ gu_tab,
                         unsigned short* __restrict__ interw) {
    const int v = gu_tab[blockIdx.x];
    if (v < 0) return;
    const int e    = v >> 16;
    const int iblk = (v >> 8) & 255;
    const int tile = v & 255;
    const int n = counts[e];

    __shared__ unsigned short s_a[128][LDW];
    __shared__ unsigned short s_bg[64][LDW];
    __shared__ unsigned short s_bu[64][LDW];
    __shared__ int s_tok[128];

    const int tid = threadIdx.x;
    if (tid < 128) {
        int tt = tile * 128 + tid;
        s_tok[tid] = btok[e * NSLOT + (tt < n ? tt : n - 1)];
    }
    __syncthreads();

    const unsigned short* asrc[4];
    unsigned aoff[4];
    #pragma unroll
    for (int t = 0; t < 4; ++t) {
        int c = tid + t * 256;
        int r = c >> 3, col = (c & 7) * 8;
        asrc[t] = xb + (size_t)s_tok[r] * HID + col;
        aoff[t] = r * LDW + col;
    }
    const float* gbase = gate + (size_t)e * ITR * HID + (size_t)iblk * 64 * HID;
    const float* ubase = up   + (size_t)e * ITR * HID + (size_t)iblk * 64 * HID;
    unsigned boff[4], loff[4];
    #pragma unroll
    for (int t = 0; t < 4; ++t) {
        int f = tid + t * 256;
        int r = f >> 4, col = (f & 15) * 4;
        boff[t] = r * HID + col;
        loff[t] = r * LDW + col;
    }

    const int lane = tid & 63;
    const int w = tid >> 6;
    const int wm = (w & 1) * 64, wn = (w >> 1) * 32;
    const int l15 = lane & 15, quad = lane >> 4;

    f32x4 accg[4][2], accu[4][2];
    #pragma unroll
    for (int m = 0; m < 4; ++m)
        #pragma unroll
        for (int nn = 0; nn < 2; ++nn) {
            accg[m][nn] = (f32x4){0.f, 0.f, 0.f, 0.f};
            accu[m][nn] = (f32x4){0.f, 0.f, 0.f, 0.f};
        }

    unsigned short* s_flat_a = &s_a[0][0];
    unsigned short* s_flat_g = &s_bg[0][0];
    unsigned short* s_flat_u = &s_bu[0][0];

    uint4 pa[4];
    float4 pg[4], pu[4];
    #pragma unroll
    for (int t = 0; t < 4; ++t) {
        pa[t] = *(const uint4*)(asrc[t]);
        pg[t] = *(const float4*)(gbase + boff[t]);
        pu[t] = *(const float4*)(ubase + boff[t]);
    }

    for (int k0 = 0; k0 < HID; k0 += BK) {
        #pragma unroll
        for (int t = 0; t < 4; ++t) {
            *(uint4*)(s_flat_a + aoff[t]) = pa[t];
            ushort4 gb, ub;
            gb.x = f2bf(pg[t].x); gb.y = f2bf(pg[t].y); gb.z = f2bf(pg[t].z); gb.w = f2bf(pg[t].w);
            ub.x = f2bf(pu[t].x); ub.y = f2bf(pu[t].y); ub.z = f2bf(pu[t].z); ub.w = f2bf(pu[t].w);
            *(ushort4*)(s_flat_g + loff[t]) = gb;
            *(ushort4*)(s_flat_u + loff[t]) = ub;
        }
        __syncthreads();
        if (k0 + BK < HID) {
            #pragma unroll
            for (int t = 0; t < 4; ++t) {
                pa[t] = *(const uint4*)(asrc[t] + k0 + BK);
                pg[t] = *(const float4*)(gbase + boff[t] + k0 + BK);
                pu[t] = *(const float4*)(ubase + boff[t] + k0 + BK);
            }
        }
        #pragma unroll
        for (int kk = 0; kk < 2; ++kk) {
            const int kc = kk * 32 + quad * 8;
            short8 af[4], bg[2], bu[2];
            #pragma unroll
            for (int m = 0; m < 4; ++m)
                af[m] = *(const short8*)&s_a[wm + m * 16 + l15][kc];
            #pragma unroll
            for (int nn = 0; nn < 2; ++nn) {
                bg[nn] = *(const short8*)&s_bg[wn + nn * 16 + l15][kc];
                bu[nn] = *(const short8*)&s_bu[wn + nn * 16 + l15][kc];
            }
            #pragma unroll
            for (int m = 0; m < 4; ++m)
                #pragma unroll
                for (int nn = 0; nn < 2; ++nn) {
                    accg[m][nn] = __builtin_amdgcn_mfma_f32_16x16x32_bf16(af[m], bg[nn], accg[m][nn], 0, 0, 0);
                    accu[m][nn] = __builtin_amdgcn_mfma_f32_16x16x32_bf16(af[m], bu[nn], accu[m][nn], 0, 0, 0);
                }
        }
        __syncthreads();
    }

    const int pos0 = off[e] + tile * 128;
    #pragma unroll
    for (int m = 0; m < 4; ++m) {
        #pragma unroll
        for (int nn = 0; nn < 2; ++nn) {
            int col = iblk * 64 + wn + nn * 16 + l15;
            #pragma unroll
            for (int r = 0; r < 4; ++r) {
                int row = wm + m * 16 + quad * 4 + r;
                float g = accg[m][nn][r], u = accu[m][nn][r];
                float s = g / (1.0f + __expf(-g));
                interw[(size_t)(pos0 + row) * ITR + col] = f2bf(s * u);
            }
        }
    }
}

// Stage 2: M=128 slots x N=128 hid cols, K=1024. grid = 8*SLOTS via dn_tab
// mode 0: write scaled partials (coalesced). mode 1: atomicAdd into out (ws-limited fallback)
__launch_bounds__(256)
__global__ void moe_down_k(const unsigned short* __restrict__ interw,
                           const float* __restrict__ down,
                           const int* __restrict__ counts,
                           const int* __restrict__ btok,
                           const float* __restrict__ bw,
                           const int* __restrict__ off,
                           const int* __restrict__ dn_tab,
                           float* __restrict__ dst,
                           int mode) {
    const int v = dn_tab[blockIdx.x];
    if (v < 0) return;
    const int e    = v >> 16;
    const int hblk = (v >> 8) & 255;
    const int tile = v & 255;
    const int n = counts[e];

    __shared__ unsigned short s_a[128][LDW];
    __shared__ unsigned short s_b[128][LDW];
    __shared__ int s_tok[128];
    __shared__ float s_w[128];

    const int tid = threadIdx.x;
    if (tid < 128) {
        int tt = tile * 128 + tid;
        bool vv = tt < n;
        s_tok[tid] = btok[e * NSLOT + (vv ? tt : n - 1)];
        s_w[tid] = vv ? bw[e * NSLOT + tt] : 0.0f;
    }
    __syncthreads();

    const int pos0 = off[e] + tile * 128;
    unsigned aoff[4], asrco[4];
    #pragma unroll
    for (int t = 0; t < 4; ++t) {
        int c = tid + t * 256;
        int r = c >> 3, col = (c & 7) * 8;
        asrco[t] = (unsigned)((pos0 + r) * ITR + col);
        aoff[t] = r * LDW + col;
    }
    const float* dbase = down + (size_t)e * HID * ITR + (size_t)hblk * 128 * ITR;
    unsigned boff[8], loff[8];
    #pragma unroll
    for (int t = 0; t < 8; ++t) {
        int f = tid + t * 256;
        int r = f >> 4, col = (f & 15) * 4;
        boff[t] = r * ITR + col;
        loff[t] = r * LDW + col;
    }

    const int lane = tid & 63;
    const int w = tid >> 6;
    const int wm = (w & 1) * 64, wn = (w >> 1) * 64;
    const int l15 = lane & 15, quad = lane >> 4;

    f32x4 acc[4][4];
    #pragma unroll
    for (int m = 0; m < 4; ++m)
        #pragma unroll
        for (int nn = 0; nn < 4; ++nn) acc[m][nn] = (f32x4){0.f, 0.f, 0.f, 0.f};

    unsigned short* s_flat_a = &s_a[0][0];
    unsigned short* s_flat_b = &s_b[0][0];

    uint4 pa[4];
    float4 pb[8];
    #pragma unroll
    for (int t = 0; t < 4; ++t) pa[t] = *(const uint4*)(interw + asrco[t]);
    #pragma unroll
    for (int t = 0; t < 8; ++t) pb[t] = *(const float4*)(dbase + boff[t]);

    for (int k0 = 0; k0 < ITR; k0 += BK) {
        #pragma unroll
        for (int t = 0; t < 4; ++t)
            *(uint4*)(s_flat_a + aoff[t]) = pa[t];
        #pragma unroll
        for (int t = 0; t < 8; ++t) {
            ushort4 b;
            b.x = f2bf(pb[t].x); b.y = f2bf(pb[t].y); b.z = f2bf(pb[t].z); b.w = f2bf(pb[t].w);
            *(ushort4*)(s_flat_b + loff[t]) = b;
        }
        __syncthreads();
        if (k0 + BK < ITR) {
            #pragma unroll
            for (int t = 0; t < 4; ++t) pa[t] = *(const uint4*)(interw + asrco[t] + k0 + BK);
            #pragma unroll
            for (int t = 0; t < 8; ++t) pb[t] = *(const float4*)(dbase + boff[t] + k0 + BK);
        }
        #pragma unroll
        for (int kk = 0; kk < 2; ++kk) {
            const int kc = kk * 32 + quad * 8;
            short8 af[4], bf[4];
            #pragma unroll
            for (int m = 0; m < 4; ++m)
                af[m] = *(const short8*)&s_a[wm + m * 16 + l15][kc];
            #pragma unroll
            for (int nn = 0; nn < 4; ++nn)
                bf[nn] = *(const short8*)&s_b[wn + nn * 16 + l15][kc];
            #pragma unroll
            for (int m = 0; m < 4; ++m)
                #pragma unroll
                for (int nn = 0; nn < 4; ++nn)
                    acc[m][nn] = __builtin_amdgcn_mfma_f32_16x16x32_bf16(af[m], bf[nn], acc[m][nn], 0, 0, 0);
        }
        __syncthreads();
    }

    if (mode == 0) {
        // coalesced scaled partials: part[pos0+row][hblk*128 + col]
        #pragma unroll
        for (int m = 0; m < 4; ++m) {
            #pragma unroll
            for (int nn = 0; nn < 4; ++nn) {
                int col = hblk * 128 + wn + nn * 16 + l15;
                #pragma unroll
                for (int r = 0; r < 4; ++r) {
                    int row = wm + m * 16 + quad * 4 + r;
                    dst[(size_t)(pos0 + row) * HID + col] = s_w[row] * acc[m][nn][r];
                }
            }
        }
    } else {
        #pragma unroll
        for (int m = 0; m < 4; ++m) {
            #pragma unroll
            for (int nn = 0; nn < 4; ++nn) {
                int col = hblk * 128 + wn + nn * 16 + l15;
                #pragma unroll
                for (int r = 0; r < 4; ++r) {
                    int row = wm + m * 16 + quad * 4 + r;
                    atomicAdd(&dst[(size_t)s_tok[row] * HID + col], s_w[row] * acc[m][nn][r]);
                }
            }
        }
    }
}

// ================= fp32 fallback (used only if ws too small) =================
#define TT 8
#define TN 128
#define TK 16
#define WPAD 20
#define IPAD 1028
#define MAXTILES (NSLOT / TT)

__global__ void route_k(const int* __restrict__ idx,
                        const float* __restrict__ wts,
                        int* __restrict__ counts,
                        int* __restrict__ btok,
                        float* __restrict__ bw) {
    int s = blockIdx.x * blockDim.x + threadIdx.x;
    if (s >= NSLOT) return;
    int e = idx[s];
    int pos = atomicAdd(&counts[e], 1);
    btok[(size_t)e * NSLOT + pos] = s / TOPK;
    bw[(size_t)e * NSLOT + pos] = wts[s];
}

__launch_bounds__(256)
__global__ void moe_k(const float* __restrict__ x,
                      const float* __restrict__ gate,
                      const float* __restrict__ up,
                      const float* __restrict__ down,
                      const int* __restrict__ counts,
                      const int* __restrict__ btok,
                      const float* __restrict__ bw,
                      float* __restrict__ out) {
    const int e = blockIdx.x / MAXTILES;
    const int tile = blockIdx.x % MAXTILES;
    const int n = counts[e];
    const int t0 = tile * TT;
    if (t0 >= n) return;

    __shared__ float s_wg[TN][WPAD];
    __shared__ float s_wu[TN][WPAD];
    __shared__ float s_it[TT][IPAD];
    __shared__ int   s_tok[TT];
    __shared__ float s_w[TT];

    const int tid = threadIdx.x;
    if (tid < TT) {
        int tt = t0 + tid;
        bool v = tt < n;
        s_tok[tid] = btok[(size_t)e * NSLOT + (v ? tt : t0)];
        s_w[tid] = v ? bw[(size_t)e * NSLOT + tt] : 0.0f;
    }
    __syncthreads();

    const int tok = tid >> 5;
    const int ic  = (tid & 31) << 2;
    const int mytok = s_tok[tok];
    const float* xrow = x + (size_t)mytok * HID;
    const float* gbase = gate + (size_t)e * ITR * HID;
    const float* ubase = up   + (size_t)e * ITR * HID;
    const float* dbase = down + (size_t)e * HID * ITR;

    for (int i0 = 0; i0 < ITR; i0 += TN) {
        float ag[4] = {0.f, 0.f, 0.f, 0.f};
        float au[4] = {0.f, 0.f, 0.f, 0.f};
        for (int k0 = 0; k0 < HID; k0 += TK) {
            #pragma unroll
            for (int j = 0; j < 2; ++j) {
                int f4 = tid + j * 256;
                int r = f4 >> 2, c = (f4 & 3) << 2;
                *(float4*)&s_wg[r][c] = *(const float4*)(gbase + (size_t)(i0 + r) * HID + k0 + c);
                *(float4*)&s_wu[r][c] = *(const float4*)(ubase + (size_t)(i0 + r) * HID + k0 + c);
            }
            __syncthreads();
            #pragma unroll
            for (int kk = 0; kk < TK; kk += 4) {
                float4 xv = *(const float4*)(xrow + k0 + kk);
                #pragma unroll
                for (int q = 0; q < 4; ++q) {
                    float4 wg = *(const float4*)&s_wg[ic + q][kk];
                    float4 wu = *(const float4*)&s_wu[ic + q][kk];
                    ag[q] += xv.x * wg.x + xv.y * wg.y + xv.z * wg.z + xv.w * wg.w;
                    au[q] += xv.x * wu.x + xv.y * wu.y + xv.z * wu.z + xv.w * wu.w;
                }
            }
            __syncthreads();
        }
        #pragma unroll
        for (int q = 0; q < 4; ++q) {
            float g = ag[q], u = au[q];
            s_it[tok][i0 + ic + q] = (g / (1.0f + __expf(-g))) * u;
        }
    }
    __syncthreads();

    const float wscale = s_w[tok];
    for (int h0 = 0; h0 < HID; h0 += TN) {
        float ac[4] = {0.f, 0.f, 0.f, 0.f};
        for (int k0 = 0; k0 < ITR; k0 += TK) {
            #pragma unroll
            for (int j = 0; j < 2; ++j) {
                int f4 = tid + j * 256;
                int r = f4 >> 2, c = (f4 & 3) << 2;
                *(float4*)&s_wg[r][c] = *(const float4*)(dbase + (size_t)(h0 + r) * ITR + k0 + c);
            }
            __syncthreads();
            #pragma unroll
            for (int kk = 0; kk < TK; kk += 4) {
                float4 xv = *(const float4*)&s_it[tok][k0 + kk];
                #pragma unroll
                for (int q = 0; q < 4; ++q) {
                    float4 wv = *(const float4*)&s_wg[ic + q][kk];
                    ac[q] += xv.x * wv.x + xv.y * wv.y + xv.z * wv.z + xv.w * wv.w;
                }
            }
            __syncthreads();
        }
        float* orow = out + (size_t)mytok * HID + h0 + ic;
        #pragma unroll
        for (int q = 0; q < 4; ++q) atomicAdd(&orow[q], wscale * ac[q]);
    }
}

extern "C" void kernel_launch(void* const* d_in, const int* in_sizes, int n_in,
                              void* d_out, int out_size, void* d_ws, size_t ws_size,
                              hipStream_t stream) {
    const float* x    = (const float*)d_in[0];
    const int*   idx  = (const int*)d_in[1];
    const float* wts  = (const float*)d_in[2];
    const float* gate = (const float*)d_in[3];
    const float* up   = (const float*)d_in[4];
    const float* down = (const float*)d_in[5];
    float* out = (float*)d_out;

    // ws layout
    const size_t off_btok  = 256;
    const size_t off_bw    = off_btok + (size_t)NEXP * NSLOT * 4;      // 128 KB
    const size_t off_offs  = off_bw + (size_t)NEXP * NSLOT * 4;        // 128 KB
    const size_t off_smap  = off_offs + 256;
    const size_t off_tabs  = off_smap + (size_t)NSLOT * 4;             // 16 KB
    const size_t off_xb    = off_tabs + 2 * 8 * SLOTS * 4;             // 5.1 KB
    const size_t off_inter = off_xb + (size_t)NTOK * HID * 2;          // 8 MB
    const size_t off_part  = off_inter + (size_t)(MAXTT * 128) * ITR * 2;  // 10.5 MB
    const size_t need_mid  = off_part;
    const size_t need_full = off_part + (size_t)(MAXTT * 128) * HID * 4;   // +42 MB

    int*   counts = (int*)d_ws;
    int*   btok   = (int*)((char*)d_ws + off_btok);
    float* bw     = (float*)((char*)d_ws + off_bw);
    int*   offs   = (int*)((char*)d_ws + off_offs);
    int*   smap   = (int*)((char*)d_ws + off_smap);
    int*   gu_tab = (int*)((char*)d_ws + off_tabs);
    int*   dn_tab = gu_tab + 8 * SLOTS;
    unsigned short* xb     = (unsigned short*)((char*)d_ws + off_xb);
    unsigned short* interw = (unsigned short*)((char*)d_ws + off_inter);
    float* part   = (float*)((char*)d_ws + off_part);

    if (ws_size >= need_mid) {
        const int full = (ws_size >= need_full);
        route_all_k<<<dim3(1), dim3(256), 0, stream>>>(idx, wts, counts, btok, bw, offs, smap, gu_tab, dn_tab);
        xconv_k<<<dim3(NTOK * HID / 4 / 256), dim3(256), 0, stream>>>(x, xb);
        if (!full) hipMemsetAsync(d_out, 0, (size_t)out_size * sizeof(float), stream);
        moe_gu_k<<<dim3(8 * SLOTS), dim3(256), 0, stream>>>(xb, gate, up, counts, btok, offs, gu_tab, interw);
        moe_down_k<<<dim3(8 * SLOTS), dim3(256), 0, stream>>>(interw, down, counts, btok, bw, offs, dn_tab,
                                                              full ? part : out, full ? 0 : 1);
        if (full)
            combine_k<<<dim3(NTOK * HID / 4 / 256), dim3(256), 0, stream>>>(part, smap, out);
    } else {
        hipMemsetAsync(d_out, 0, (size_t)out_size * sizeof(float), stream);
        hipMemsetAsync(counts, 0, 256, stream);
        route_k<<<dim3((NSLOT + 255) / 256), dim3(256), 0, stream>>>(idx, wts, counts, btok, bw);
        moe_k<<<dim3(NEXP * MAXTILES), dim3(256), 0, stream>>>(x, gate, up, down, counts, btok, bw, out);
    }
}